// Round 1
// baseline (364.252 us; speedup 1.0000x reference)
//
#include <hip/hip_runtime.h>

#define NB 64
#define NS 2048
#define ND 512
#define TS 64    // timesteps per block
#define NWAVES 4

// Kernel 1: raw squared L2 distances between consecutive timesteps + per-batch max.
// One wave per timestep; lane i holds float4 columns [4i,4i+4) and [4(i+64),4(i+64)+4).
__global__ __launch_bounds__(256) void l2_dist_kernel(const float* __restrict__ x,
                                                      float* __restrict__ out,
                                                      float* __restrict__ maxbuf) {
    const int b     = blockIdx.y;
    const int chunk = blockIdx.x;
    const int wave  = threadIdx.x >> 6;
    const int lane  = threadIdx.x & 63;

    __shared__ float wmaxes[NWAVES];

    const float* xb = x + (size_t)b * NS * ND;
    float wmax = 0.0f;

    #pragma unroll
    for (int i = 0; i < TS / NWAVES; ++i) {
        const int s = chunk * TS + i * NWAVES + wave;
        float sum = 0.0f;
        if (s > 0) {  // wave-uniform branch; s==0 => d=0
            const float4* cur = (const float4*)(xb + (size_t)s * ND);
            const float4* prv = (const float4*)(xb + (size_t)(s - 1) * ND);
            float4 c0 = cur[lane];
            float4 p0 = prv[lane];
            float4 c1 = cur[lane + 64];
            float4 p1 = prv[lane + 64];
            float dx;
            dx = c0.x - p0.x; sum += dx * dx;
            dx = c0.y - p0.y; sum += dx * dx;
            dx = c0.z - p0.z; sum += dx * dx;
            dx = c0.w - p0.w; sum += dx * dx;
            dx = c1.x - p1.x; sum += dx * dx;
            dx = c1.y - p1.y; sum += dx * dx;
            dx = c1.z - p1.z; sum += dx * dx;
            dx = c1.w - p1.w; sum += dx * dx;
        }
        // 64-lane butterfly reduce: all lanes end with the full sum
        #pragma unroll
        for (int m = 32; m >= 1; m >>= 1)
            sum += __shfl_xor(sum, m, 64);
        if (lane == 0) out[(size_t)b * NS + s] = sum;
        wmax = fmaxf(wmax, sum);
    }

    if (lane == 0) wmaxes[wave] = wmax;
    __syncthreads();
    if (threadIdx.x == 0) {
        float m = wmaxes[0];
        #pragma unroll
        for (int w = 1; w < NWAVES; ++w) m = fmaxf(m, wmaxes[w]);
        // d >= 0 always, so IEEE float order == unsigned int order
        atomicMax((unsigned int*)&maxbuf[b], __float_as_uint(m));
    }
}

// Kernel 2: normalize each batch row by its max (in place on d_out).
__global__ __launch_bounds__(256) void l2_norm_kernel(float* __restrict__ out,
                                                      const float* __restrict__ maxbuf) {
    const int b = blockIdx.x;
    const float mv = maxbuf[b];
    for (int j = threadIdx.x; j < NS; j += 256)
        out[(size_t)b * NS + j] /= mv;
}

extern "C" void kernel_launch(void* const* d_in, const int* in_sizes, int n_in,
                              void* d_out, int out_size, void* d_ws, size_t ws_size,
                              hipStream_t stream) {
    const float* x   = (const float*)d_in[0];
    float* out       = (float*)d_out;
    float* maxbuf    = (float*)d_ws;  // 64 floats

    // d_ws is poisoned to 0xAA (negative floats / huge uints) — must zero for atomicMax
    hipMemsetAsync(maxbuf, 0, NB * sizeof(float), stream);

    dim3 grid(NS / TS, NB);
    l2_dist_kernel<<<grid, dim3(256), 0, stream>>>(x, out, maxbuf);
    l2_norm_kernel<<<dim3(NB), dim3(256), 0, stream>>>(out, maxbuf);
}

// Round 2
// 359.659 us; speedup vs baseline: 1.0128x; 1.0128x over previous
//
#include <hip/hip_runtime.h>

#define NB 64
#define NS 2048
#define ND 512
#define TS 64            // timesteps per block in kernel 1
#define NWAVES 4
#define NCHUNK (NS / TS) // 32 chunk-maxes per batch

// Kernel 1: raw squared L2 distances between consecutive timesteps.
// One wave per timestep; lane i holds float4 columns [4i,4i+4) and [4(i+64),4(i+64)+4).
// Each block writes its own chunk-max slot — no atomics, no init required.
__global__ __launch_bounds__(256, 4) void l2_dist_kernel(const float* __restrict__ x,
                                                         float* __restrict__ out,
                                                         float* __restrict__ chunkmax) {
    const int b     = blockIdx.y;
    const int chunk = blockIdx.x;
    const int wave  = threadIdx.x >> 6;
    const int lane  = threadIdx.x & 63;

    __shared__ float wmaxes[NWAVES];

    const float* xb = x + (size_t)b * NS * ND;
    float wmax = 0.0f;

    #pragma unroll 4
    for (int i = 0; i < TS / NWAVES; ++i) {
        const int s = chunk * TS + i * NWAVES + wave;
        float sum = 0.0f;
        if (s > 0) {  // wave-uniform; only (chunk 0, wave 0, i 0) skips
            const float4* cur = (const float4*)(xb + (size_t)s * ND);
            const float4* prv = (const float4*)(xb + (size_t)(s - 1) * ND);
            float4 c0 = cur[lane];
            float4 p0 = prv[lane];
            float4 c1 = cur[lane + 64];
            float4 p1 = prv[lane + 64];
            float dx;
            dx = c0.x - p0.x; sum += dx * dx;
            dx = c0.y - p0.y; sum += dx * dx;
            dx = c0.z - p0.z; sum += dx * dx;
            dx = c0.w - p0.w; sum += dx * dx;
            dx = c1.x - p1.x; sum += dx * dx;
            dx = c1.y - p1.y; sum += dx * dx;
            dx = c1.z - p1.z; sum += dx * dx;
            dx = c1.w - p1.w; sum += dx * dx;
        }
        // 64-lane butterfly: all lanes end with the full row sum
        #pragma unroll
        for (int m = 32; m >= 1; m >>= 1)
            sum += __shfl_xor(sum, m, 64);
        if (lane == 0) out[(size_t)b * NS + s] = sum;
        wmax = fmaxf(wmax, sum);
    }

    if (lane == 0) wmaxes[wave] = wmax;
    __syncthreads();
    if (threadIdx.x == 0) {
        float m = wmaxes[0];
        #pragma unroll
        for (int w = 1; w < NWAVES; ++w) m = fmaxf(m, wmaxes[w]);
        chunkmax[b * NCHUNK + chunk] = m;  // private slot, plain store
    }
}

// Kernel 2: reduce the 32 chunk-maxes per batch, normalize row in place.
// grid = (2, 64); each block handles 1024 floats (one float4 per thread).
__global__ __launch_bounds__(256) void l2_norm_kernel(float* __restrict__ out,
                                                      const float* __restrict__ chunkmax) {
    const int b    = blockIdx.y;
    const int half = blockIdx.x;
    const int tid  = threadIdx.x;

    __shared__ float smax;
    if (tid < 64) {  // wave 0 only
        float v = (tid < NCHUNK) ? chunkmax[b * NCHUNK + tid] : 0.0f;
        #pragma unroll
        for (int m = 16; m >= 1; m >>= 1)
            v = fmaxf(v, __shfl_xor(v, m, 64));
        if (tid == 0) smax = v;
    }
    __syncthreads();
    const float inv = 1.0f / smax;

    float4* row = (float4*)(out + (size_t)b * NS) + half * 256 + tid;
    float4 v = *row;
    v.x *= inv; v.y *= inv; v.z *= inv; v.w *= inv;
    *row = v;
}

extern "C" void kernel_launch(void* const* d_in, const int* in_sizes, int n_in,
                              void* d_out, int out_size, void* d_ws, size_t ws_size,
                              hipStream_t stream) {
    const float* x  = (const float*)d_in[0];
    float* out      = (float*)d_out;
    float* chunkmax = (float*)d_ws;  // 64*32 floats, fully overwritten by k1

    l2_dist_kernel<<<dim3(NCHUNK, NB), dim3(256), 0, stream>>>(x, out, chunkmax);
    l2_norm_kernel<<<dim3(2, NB), dim3(256), 0, stream>>>(out, chunkmax);
}

// Round 3
// 356.027 us; speedup vs baseline: 1.0231x; 1.0102x over previous
//
#include <hip/hip_runtime.h>

#define NB 64
#define NS 2048
#define ND 512
#define K  32                 // timesteps per wave run
#define WPB 4                 // waves per block
#define GPB (NS / K / WPB)    // wave-runs per batch / waves per block = blocks per batch (16)
#define NRUN (NS / K)         // runs (chunk-maxes) per batch = 64

// Kernel 1: each wave owns K consecutive timesteps of one batch, full D width.
// Lane holds cols [8*lane, 8*lane+8) as two float4s; previous row stays in
// registers, so every input row is fetched from HBM exactly once (+1 overlap
// row per run). d[0]=0 falls out naturally (prev initialized to row 0 itself).
__global__ __launch_bounds__(256, 4) void l2_dist_kernel(const float* __restrict__ x,
                                                         float* __restrict__ out,
                                                         float* __restrict__ runmax) {
    const int b    = blockIdx.y;
    const int wave = threadIdx.x >> 6;
    const int lane = threadIdx.x & 63;
    const int g    = blockIdx.x * WPB + wave;   // run index within batch (0..63)
    const int s0   = g * K;

    const float4* xb = (const float4*)(x + (size_t)b * NS * ND);  // ND/4 float4s per row
    const int RW = ND / 4;  // 128 float4s per row
    const int c0 = lane * 2;

    // init prev = row max(s0-1, 0); for s0==0 this makes d[0] = 0 branchlessly
    const int sp = (s0 > 0) ? s0 - 1 : 0;
    float4 p0 = xb[(size_t)sp * RW + c0];
    float4 p1 = xb[(size_t)sp * RW + c0 + 1];

    float wmax = 0.0f;

    #pragma unroll 4
    for (int i = 0; i < K; ++i) {
        const int s = s0 + i;
        float4 c0v = xb[(size_t)s * RW + c0];
        float4 c1v = xb[(size_t)s * RW + c0 + 1];
        float dx, sum = 0.0f;
        dx = c0v.x - p0.x; sum += dx * dx;
        dx = c0v.y - p0.y; sum += dx * dx;
        dx = c0v.z - p0.z; sum += dx * dx;
        dx = c0v.w - p0.w; sum += dx * dx;
        dx = c1v.x - p1.x; sum += dx * dx;
        dx = c1v.y - p1.y; sum += dx * dx;
        dx = c1v.z - p1.z; sum += dx * dx;
        dx = c1v.w - p1.w; sum += dx * dx;
        p0 = c0v; p1 = c1v;
        // 64-lane butterfly: all lanes end with the full row sum
        #pragma unroll
        for (int m = 32; m >= 1; m >>= 1)
            sum += __shfl_xor(sum, m, 64);
        if (lane == 0) out[(size_t)b * NS + s] = sum;
        wmax = fmaxf(wmax, sum);
    }

    if (lane == 0) runmax[b * NRUN + g] = wmax;  // private slot, no atomics
}

// Kernel 2: reduce the 64 run-maxes per batch, normalize row in place.
// grid = (2, 64); each block handles 1024 floats (one float4 per thread).
__global__ __launch_bounds__(256) void l2_norm_kernel(float* __restrict__ out,
                                                      const float* __restrict__ runmax) {
    const int b    = blockIdx.y;
    const int half = blockIdx.x;
    const int tid  = threadIdx.x;

    __shared__ float smax;
    if (tid < 64) {  // wave 0: butterfly-max over the 64 run maxes
        float v = runmax[b * NRUN + tid];
        #pragma unroll
        for (int m = 32; m >= 1; m >>= 1)
            v = fmaxf(v, __shfl_xor(v, m, 64));
        if (tid == 0) smax = v;
    }
    __syncthreads();
    const float inv = 1.0f / smax;

    float4* row = (float4*)(out + (size_t)b * NS) + half * 256 + tid;
    float4 v = *row;
    v.x *= inv; v.y *= inv; v.z *= inv; v.w *= inv;
    *row = v;
}

extern "C" void kernel_launch(void* const* d_in, const int* in_sizes, int n_in,
                              void* d_out, int out_size, void* d_ws, size_t ws_size,
                              hipStream_t stream) {
    const float* x = (const float*)d_in[0];
    float* out     = (float*)d_out;
    float* runmax  = (float*)d_ws;  // 64*64 floats, fully overwritten by k1

    l2_dist_kernel<<<dim3(GPB, NB), dim3(256), 0, stream>>>(x, out, runmax);
    l2_norm_kernel<<<dim3(2, NB), dim3(256), 0, stream>>>(out, runmax);
}